// Round 12
// baseline (168.649 us; speedup 1.0000x reference)
//
#include <hip/hip_runtime.h>
#include <hip/hip_bf16.h>

#define BB 8
#define CIN 512
#define COUT 512
#define HH 64
#define WW 64

#define AFF_SCALE 0.044194173824159216f     // 1/sqrt(512)
#define CONV_SCALE 0.014731391274719736f    // 1/sqrt(4608)
#define CONV_SCALE2 (1.0f/4608.0f)

typedef short s16x8 __attribute__((ext_vector_type(8)));
typedef float f32x16 __attribute__((ext_vector_type(16)));

__device__ __forceinline__ unsigned short f2bf(float f) {
  __hip_bfloat16 h = __float2bfloat16(f);
  return *reinterpret_cast<unsigned short*>(&h);
}

// zero-register global->LDS DMA, 16B per lane; LDS dest = uniform base + lane*16
__device__ __forceinline__ void gload_lds16(const void* g, void* l) {
  __builtin_amdgcn_global_load_lds(
      (const __attribute__((address_space(1))) unsigned int*)g,
      (__attribute__((address_space(3))) unsigned int*)l, 16, 0, 0);
}

// ---------------------------------------------------------------------------
// smod[b*CIN+ic] = dot(style[b,:], w_affine[ic,:]) * AFF_SCALE + ba[ic]
// ---------------------------------------------------------------------------
__global__ __launch_bounds__(256) void affine_kernel(
    const float* __restrict__ style, const float* __restrict__ wa,
    const float* __restrict__ ba, float* __restrict__ smod) {
  int wid  = (blockIdx.x << 2) + (threadIdx.x >> 6);
  int lane = threadIdx.x & 63;
  int b  = wid >> 9;
  int ic = wid & 511;
  const float* s = style + b * CIN;
  const float* w = wa + (size_t)ic * CIN;
  float sum = 0.f;
#pragma unroll
  for (int k = 0; k < CIN / 64; ++k) sum += s[lane + 64 * k] * w[lane + 64 * k];
#pragma unroll
  for (int off = 32; off; off >>= 1) sum += __shfl_down(sum, off, 64);
  if (lane == 0) smod[wid] = sum * AFF_SCALE + ba[ic];
}

// ---------------------------------------------------------------------------
// wsq[oc*CIN+ic] = sum_k w_conv[oc,ic,k]^2
// ---------------------------------------------------------------------------
__global__ __launch_bounds__(256) void wsq_kernel(
    const float* __restrict__ wc, float* __restrict__ wsq) {
  int i = blockIdx.x * 256 + threadIdx.x;
  const float* p = wc + (size_t)i * 9;
  float s = 0.f;
#pragma unroll
  for (int k = 0; k < 9; ++k) { float v = p[k]; s += v * v; }
  wsq[i] = s;
}

// ---------------------------------------------------------------------------
// demod[b*COUT+oc] = rsqrt(CS2 * sum_ic smod^2 * wsq + eps) * CS
// ---------------------------------------------------------------------------
__global__ __launch_bounds__(256) void demod_kernel(
    const float* __restrict__ smod, const float* __restrict__ wsq,
    float* __restrict__ demod) {
  int wid  = (blockIdx.x << 2) + (threadIdx.x >> 6);
  int lane = threadIdx.x & 63;
  int b  = wid >> 9;
  int oc = wid & 511;
  const float* s = smod + b * CIN;
  const float* w = wsq + (size_t)oc * CIN;
  float sum = 0.f;
#pragma unroll
  for (int k = 0; k < CIN / 64; ++k) {
    float sv = s[lane + 64 * k];
    sum += sv * sv * w[lane + 64 * k];
  }
#pragma unroll
  for (int off = 32; off; off >>= 1) sum += __shfl_down(sum, off, 64);
  if (lane == 0) demod[wid] = rsqrtf(sum * CONV_SCALE2 + 1e-8f) * CONV_SCALE;
}

// ---------------------------------------------------------------------------
// premod: xt[b][g][y][x][ic32] bf16 = input[b][ic][y][x] * smod[b][ic]
// ---------------------------------------------------------------------------
__global__ __launch_bounds__(256) void premod_kernel(
    const float* __restrict__ xin, const float* __restrict__ smod,
    ushort* __restrict__ xt) {
  int n = blockIdx.x * 256 + threadIdx.x;   // < 2,097,152
  int kg = n & 3;
  int x  = (n >> 2) & 63;
  int y  = (n >> 8) & 63;
  int g  = (n >> 14) & 15;
  int b  = n >> 18;
  int ic0 = g * 32 + kg * 8;
  const float* sp = smod + b * CIN + ic0;
  const float* xp = xin + (((size_t)b * CIN + ic0) * HH + y) * WW + x;
  s16x8 o;
#pragma unroll
  for (int j = 0; j < 8; ++j) {
    float v = xp[(size_t)j * HH * WW] * sp[j];
    o[j] = (short)f2bf(v);
  }
  *(s16x8*)(xt + (size_t)n * 8) = o;
}

// ---------------------------------------------------------------------------
// wpack (32x32x16 A-fragment order, POSITION-ordered taps):
//   slot p in [0,9) holds tap (kh = p%3, kw = p/3)  [dy = p%3, dx = p/3]
//   wfrag[widx][mf][ks][l][8], element = wc[oc = mf*32 + (l&31)]
//                                          [ic = g*32 + ks*16 + 8*(l>>5) + j]
//                                          [kh][kw],  widx = g*9 + p
// ---------------------------------------------------------------------------
__global__ __launch_bounds__(256) void wpack_kernel(
    const float* __restrict__ wc, ushort* __restrict__ wfrag) {
  int n = blockIdx.x * 256 + threadIdx.x;   // < 294,912 = 144*16*2*64
  int l    = n & 63;
  int ks   = (n >> 6) & 1;
  int mf   = (n >> 7) & 15;
  int widx = n >> 11;           // 0..143
  int g = widx / 9, p = widx % 9;
  int kh = p % 3, kw = p / 3;   // position-order storage
  int oc  = mf * 32 + (l & 31);
  int ic0 = g * 32 + ks * 16 + 8 * (l >> 5);
  s16x8 o;
#pragma unroll
  for (int j = 0; j < 8; ++j) {
    float v = wc[((size_t)oc * CIN + ic0 + j) * 9 + kh * 3 + kw];
    o[j] = (short)f2bf(v);
  }
  *(s16x8*)(wfrag + (size_t)n * 8) = o;
}

// ---------------------------------------------------------------------------
// conv_mfma (R12): 3 waves/SIMD occupancy experiment with traffic held flat.
// Wave tile 2m x 2n (64oc x 1row x 64px), acc = 64 AGPR; block 256 thr =
// 128oc x 2rows; grid 1024 (4ocb x 8b x 32yt); __launch_bounds__(256,3).
// Weights per-wave global->VGPR, 4-slot half ping-pong (distance 2 positions,
// slot = H%4; 18 halves/g => actuals rotate by 2 per GBODY, 36/iter wraps).
// B JIT per position with one-position lookahead (b0/b1). xs (4 rows) staged
// at p3 via DMA; g-end barrier = counted vmcnt(24) (drains exactly the 4 xs
// DMAs, keeps all 24 younger weight loads in flight). Position-ordered wfrag.
// ---------------------------------------------------------------------------
#define XS_ROW 4224                 // 66 cols * 4 kg * 16 B
#define XS_BUF (4 * XS_ROW)         // 16896 B per buffer

#define MFMA1(A_, B_, C_) __builtin_amdgcn_mfma_f32_32x32x16_bf16(A_, B_, C_, 0, 0, 0)

// one k-half: 4 MFMAs (2 m-frags x 2 n-frags); S_ frags = [ph*2 + ks]
#define MH4(W_, S_, KS) \
  __builtin_amdgcn_s_setprio(1); \
  acc[0][0] = MFMA1(W_[0], S_[0 + (KS)], acc[0][0]); \
  acc[1][0] = MFMA1(W_[1], S_[0 + (KS)], acc[1][0]); \
  acc[0][1] = MFMA1(W_[0], S_[2 + (KS)], acc[0][1]); \
  acc[1][1] = MFMA1(W_[1], S_[2 + (KS)], acc[1][1]); \
  __builtin_amdgcn_s_setprio(0);

// weight prefetch: slot W_ <- (position P within current g, k-slice KS)
#define WPRE2(W_, P, KS) \
  W_[0] = *(const s16x8*)(wg + (size_t)(P) * 32768 + (KS) * 1024); \
  W_[1] = *(const s16x8*)(wg + (size_t)(P) * 32768 + 2048 + (KS) * 1024);

// B-fragment load for position P: xs row (wr + P%3), x-shift P/3
#define BLOAD(S_, P) \
  S_[0] = *(const s16x8*)(xs_r + (wr + (P) % 3) * XS_ROW + addrV[0][(P) / 3][0]); \
  S_[1] = *(const s16x8*)(xs_r + (wr + (P) % 3) * XS_ROW + addrV[0][(P) / 3][1]); \
  S_[2] = *(const s16x8*)(xs_r + (wr + (P) % 3) * XS_ROW + addrV[1][(P) / 3][0]); \
  S_[3] = *(const s16x8*)(xs_r + (wr + (P) % 3) * XS_ROW + addrV[1][(P) / 3][1]);

// g-end barrier: counted vmcnt(24) = the 24 weight loads issued after the
// 4 xs staging DMAs (p3 tail + p4..p8); drains exactly the xs DMAs.
#define GBARRIER \
  __builtin_amdgcn_sched_barrier(0); \
  asm volatile("s_waitcnt vmcnt(24) lgkmcnt(0)" ::: "memory"); \
  __builtin_amdgcn_sched_barrier(0); \
  __builtin_amdgcn_s_barrier(); \
  __builtin_amdgcn_sched_barrier(0);

// Even positions use (W0_,W1_), odd use (W2_,W3_); prefetch refills the slot
// just consumed with the half 2 positions ahead (same slot mod 4).
#define GBODY(GG, W0_, W1_, W2_, W3_, TAILC) \
{ \
  const char* xs_r = (const char*)lds + (GG) * XS_BUF; \
  char* xs_w = lds + ((GG) ^ 1) * XS_BUF; \
  const char* wg = wl + (size_t)(g2 * 18 + (GG) * 9) * 32768; \
  BLOAD(b0, 0) \
  /*p0*/ MH4(W0_, b0, 0) WPRE2(W0_, 2, 0) BLOAD(b1, 1) \
         MH4(W1_, b0, 1) WPRE2(W1_, 2, 1) \
  /*p1*/ MH4(W2_, b1, 0) WPRE2(W2_, 3, 0) BLOAD(b0, 2) \
         MH4(W3_, b1, 1) WPRE2(W3_, 3, 1) \
  /*p2*/ MH4(W0_, b0, 0) WPRE2(W0_, 4, 0) BLOAD(b1, 3) \
         MH4(W1_, b0, 1) WPRE2(W1_, 4, 1) \
  /*p3*/ if (TAILC) stage4(xtb, (size_t)(b * 16 + g2 * 2 + (GG) + 1) * 262144, srcoff, xs_w, lds_woff, y0); \
         MH4(W2_, b1, 0) WPRE2(W2_, 5, 0) BLOAD(b0, 4) \
         MH4(W3_, b1, 1) WPRE2(W3_, 5, 1) \
  /*p4*/ MH4(W0_, b0, 0) WPRE2(W0_, 6, 0) BLOAD(b1, 5) \
         MH4(W1_, b0, 1) WPRE2(W1_, 6, 1) \
  /*p5*/ MH4(W2_, b1, 0) WPRE2(W2_, 7, 0) BLOAD(b0, 6) \
         MH4(W3_, b1, 1) WPRE2(W3_, 7, 1) \
  /*p6*/ MH4(W0_, b0, 0) WPRE2(W0_, 8, 0) BLOAD(b1, 7) \
         MH4(W1_, b0, 1) WPRE2(W1_, 8, 1) \
  /*p7*/ MH4(W2_, b1, 0) WPRE2(W2_, 9, 0) BLOAD(b0, 8) \
         MH4(W3_, b1, 1) WPRE2(W3_, 9, 1) \
  /*p8*/ MH4(W0_, b0, 0) WPRE2(W0_, 10, 0) \
         MH4(W1_, b0, 1) WPRE2(W1_, 10, 1) \
  if (TAILC) { GBARRIER } \
}

__device__ __forceinline__ void stage4(const char* xtb, size_t gbase, int srcoff,
                                       char* xs_w, int lds_woff, int y0) {
  __builtin_amdgcn_sched_barrier(0);
#pragma unroll
  for (int r = 0; r < 4; ++r) {
    int gy = y0 - 1 + r;
    if (gy >= 0 && gy < HH)
      gload_lds16(xtb + gbase + (size_t)gy * 4096 + srcoff,
                  xs_w + r * XS_ROW + lds_woff);
  }
  __builtin_amdgcn_sched_barrier(0);
}

__global__ __launch_bounds__(256, 3) void conv_mfma(
    const ushort* __restrict__ xt,     // [8][16][64][64][32] bf16
    const ushort* __restrict__ wfrag,  // [144][16][2][64][8] bf16
    const float* __restrict__ demod,
    float* __restrict__ out) {
  __shared__ char lds[2 * XS_BUF];    // 33792 B -> 3 blocks/CU (LDS allows 4)

  int tid = threadIdx.x;
  int l = tid & 63, w = tid >> 6;
  int wm = w >> 1, wr = w & 1;        // oc-half (64oc), output row within block
  int bid = blockIdx.x;
  int ocb = bid & 3;                  // bid&7 -> XCD sees one ocb (L2-resident)
  int b   = (bid >> 2) & 7;
  int yt  = bid >> 5;                 // 0..31
  int y0  = yt * 2;

  f32x16 acc[2][2];
#pragma unroll
  for (int i = 0; i < 2; ++i)
#pragma unroll
    for (int j = 0; j < 2; ++j)
#pragma unroll
      for (int e = 0; e < 16; ++e) acc[i][j][e] = 0.f;

  // zero always-zero halo COLUMNS (col 0 -> chunks 0..3, col 65 -> 260..263)
  if (tid < 64) {
    int buf = tid & 1, side = (tid >> 1) & 1, kgz = (tid >> 2) & 3, r = (tid >> 4) & 3;
    int chunk = side ? (260 + kgz) : kgz;
    *(int4*)(lds + buf * XS_BUF + r * XS_ROW + chunk * 16) = int4{0, 0, 0, 0};
  }
  // zero y-halo ROWS for edge blocks (never re-staged -> stay zero)
  if (y0 == 0) {
    for (int i = tid; i < 528; i += 256) {
      int buf = i & 1, chunk = i >> 1;
      *(int4*)(lds + buf * XS_BUF + chunk * 16) = int4{0, 0, 0, 0};
    }
  }
  if (y0 == 62) {
    for (int i = tid; i < 528; i += 256) {
      int buf = i & 1, chunk = i >> 1;
      *(int4*)(lds + buf * XS_BUF + 3 * XS_ROW + chunk * 16) = int4{0, 0, 0, 0};
    }
  }

  // B-fragment read offsets (swizzled): col = ph*32 + (l&31) + dxi,
  // kg = (l>>5) + 2*ks;  addr = (col*4 + (kg ^ ((col>>1)&3))) * 16
  int addrV[2][3][2];
  {
    int lm = l & 31, kh2 = l >> 5;
#pragma unroll
    for (int ph = 0; ph < 2; ++ph)
#pragma unroll
      for (int dxi = 0; dxi < 3; ++dxi)
#pragma unroll
        for (int ks = 0; ks < 2; ++ks) {
          int col = ph * 32 + lm + dxi;                    // 0..65
          int kg  = kh2 + 2 * ks;
          addrV[ph][dxi][ks] = (col * 4 + (kg ^ ((col >> 1) & 3))) * 16;
        }
  }

  // xs staging: wave w covers quarter w of each row; per-lane PRE-SWIZZLED
  // global source offset within a 4KB xt row (verified R5-R11)
  int col_s = 1 + w * 16 + (l >> 2);
  int srcoff = (col_s - 1) * 64 + ((l & 3) ^ ((col_s >> 1) & 3)) * 16;
  int lds_woff = 64 + w * 1024;   // + r*XS_ROW (+buf*XS_BUF)

  const char* xtb = (const char*)xt;
  // per-lane weight base for this wave's 2 m-frags (mf = ocb*4 + wm*2 + q):
  //   position P of g: wl + (g*9+P)*32768 + q*2048 + ks*1024
  const char* wl = (const char*)wfrag + (size_t)(ocb * 4 + wm * 2) * 2048 + (size_t)l * 16;

  // weight slot prologue: H0..H3 = (p0,ks0),(p0,ks1),(p1,ks0),(p1,ks1)
  s16x8 wSA[2], wSB[2], wSC[2], wSD[2];
  wSA[0] = *(const s16x8*)(wl);
  wSA[1] = *(const s16x8*)(wl + 2048);
  wSB[0] = *(const s16x8*)(wl + 1024);
  wSB[1] = *(const s16x8*)(wl + 3072);
  wSC[0] = *(const s16x8*)(wl + 32768);
  wSC[1] = *(const s16x8*)(wl + 32768 + 2048);
  wSD[0] = *(const s16x8*)(wl + 32768 + 1024);
  wSD[1] = *(const s16x8*)(wl + 32768 + 3072);

  // prologue: stage g=0 into buffer 0
  {
    size_t gbase = (size_t)(b * 16) * 262144;
#pragma unroll
    for (int r = 0; r < 4; ++r) {
      int gy = y0 - 1 + r;
      if (gy >= 0 && gy < HH)
        gload_lds16(xtb + gbase + (size_t)gy * 4096 + srcoff,
                    lds + r * XS_ROW + lds_woff);
    }
  }
  __syncthreads();

  s16x8 b0[4], b1[4];

  for (int g2 = 0; g2 < 8; ++g2) {
    GBODY(0, wSA, wSB, wSC, wSD, true)
    GBODY(1, wSC, wSD, wSA, wSB, (g2 < 7))
  }

  // ---- epilogue: demod scale + store ----
  // C/D 32x32: col = l&31, row = (reg&3) + 8*(reg>>2) + 4*(l>>5)
  int gy = y0 + wr;
  int colbase = l & 31;
  int rowadd = 4 * (l >> 5);
#pragma unroll
  for (int q = 0; q < 2; ++q) {
#pragma unroll
    for (int reg = 0; reg < 16; ++reg) {
      int row = (reg & 3) + 8 * (reg >> 2) + rowadd;
      int oc = ocb * 128 + (wm * 2 + q) * 32 + row;
      float dm = demod[b * COUT + oc];
      size_t obase = ((size_t)(b * COUT + oc)) * 4096 + gy * 64;
      out[obase + colbase]      = acc[q][0][reg] * dm;
      out[obase + 32 + colbase] = acc[q][1][reg] * dm;
    }
  }
}

// ---------------------------------------------------------------------------
extern "C" void kernel_launch(void* const* d_in, const int* in_sizes, int n_in,
                              void* d_out, int out_size, void* d_ws, size_t ws_size,
                              hipStream_t stream) {
  const float* input = (const float*)d_in[0];  // [8,512,64,64]
  const float* style = (const float*)d_in[1];  // [8,512]
  const float* wa    = (const float*)d_in[2];  // [512,512]
  const float* ba    = (const float*)d_in[3];  // [1,512]
  const float* wconv = (const float*)d_in[4];  // [512,512,3,3]
  float* out = (float*)d_out;

  float* smod  = (float*)d_ws;                    // 4096 f
  float* demod = smod + BB * CIN;                 // 4096 f
  float* wsq   = demod + BB * COUT;               // 262144 f
  ushort* wfrag = (ushort*)(wsq + (size_t)COUT * CIN);   // 2,359,296 us (4.5 MB)
  ushort* xt    = wfrag + (size_t)16 * 9 * 32 * 64 * 8;  // 16,777,216 us (32 MB)

  affine_kernel<<<BB * CIN / 4, 256, 0, stream>>>(style, wa, ba, smod);
  wsq_kernel<<<COUT * CIN / 256, 256, 0, stream>>>(wconv, wsq);
  demod_kernel<<<BB * COUT / 4, 256, 0, stream>>>(smod, wsq, demod);
  wpack_kernel<<<16 * 9 * 32 * 64 / 256, 256, 0, stream>>>(wconv, wfrag);
  premod_kernel<<<BB * 16 * 64 * 64 * 4 / 256, 256, 0, stream>>>(input, smod, xt);
  conv_mfma<<<4 * BB * 32, 256, 0, stream>>>(xt, wfrag, demod, out);
}

// Round 15
// 146.542 us; speedup vs baseline: 1.1509x; 1.1509x over previous
//
#include <hip/hip_runtime.h>
#include <hip/hip_bf16.h>

#define BB 8
#define CIN 512
#define COUT 512
#define HH 64
#define WW 64

#define AFF_SCALE 0.044194173824159216f     // 1/sqrt(512)
#define CONV_SCALE 0.014731391274719736f    // 1/sqrt(4608)
#define CONV_SCALE2 (1.0f/4608.0f)

typedef short s16x8 __attribute__((ext_vector_type(8)));
typedef float f32x16 __attribute__((ext_vector_type(16)));

__device__ __forceinline__ unsigned short f2bf(float f) {
  __hip_bfloat16 h = __float2bfloat16(f);
  return *reinterpret_cast<unsigned short*>(&h);
}

// zero-register global->LDS DMA, 16B per lane; LDS dest = uniform base + lane*16
__device__ __forceinline__ void gload_lds16(const void* g, void* l) {
  __builtin_amdgcn_global_load_lds(
      (const __attribute__((address_space(1))) unsigned int*)g,
      (__attribute__((address_space(3))) unsigned int*)l, 16, 0, 0);
}

// ---------------------------------------------------------------------------
// prep1: fused {affine | wsq | wpack}  (independent passes, block-ranged)
// ---------------------------------------------------------------------------
__global__ __launch_bounds__(256) void prep1_kernel(
    const float* __restrict__ style, const float* __restrict__ wa,
    const float* __restrict__ ba, float* __restrict__ smod,
    const float* __restrict__ wc, float* __restrict__ wsq,
    ushort* __restrict__ wfrag) {
  int bb = blockIdx.x;
  if (bb < 1024) {
    int wid  = (bb << 2) + (threadIdx.x >> 6);
    int lane = threadIdx.x & 63;
    int b  = wid >> 9;
    int ic = wid & 511;
    const float* s = style + b * CIN;
    const float* w = wa + (size_t)ic * CIN;
    float sum = 0.f;
#pragma unroll
    for (int k = 0; k < CIN / 64; ++k) sum += s[lane + 64 * k] * w[lane + 64 * k];
#pragma unroll
    for (int off = 32; off; off >>= 1) sum += __shfl_down(sum, off, 64);
    if (lane == 0) smod[wid] = sum * AFF_SCALE + ba[ic];
  } else if (bb < 2048) {
    int i = (bb - 1024) * 256 + threadIdx.x;
    const float* p = wc + (size_t)i * 9;
    float s = 0.f;
#pragma unroll
    for (int k = 0; k < 9; ++k) { float v = p[k]; s += v * v; }
    wsq[i] = s;
  } else {
    int n = (bb - 2048) * 256 + threadIdx.x;   // < 294,912 = 144*16*2*64
    int l    = n & 63;
    int ks   = (n >> 6) & 1;
    int mf   = (n >> 7) & 15;
    int widx = n >> 11;           // 0..143
    int g = widx / 9, p = widx % 9;
    int kh = p % 3, kw = p / 3;   // position-order storage
    int oc  = mf * 32 + (l & 31);
    int ic0 = g * 32 + ks * 16 + 8 * (l >> 5);
    s16x8 o;
#pragma unroll
    for (int j = 0; j < 8; ++j) {
      float v = wc[((size_t)oc * CIN + ic0 + j) * 9 + kh * 3 + kw];
      o[j] = (short)f2bf(v);
    }
    *(s16x8*)(wfrag + (size_t)n * 8) = o;
  }
}

// ---------------------------------------------------------------------------
// prep2: fused {demod | premod}
// ---------------------------------------------------------------------------
__global__ __launch_bounds__(256) void prep2_kernel(
    const float* __restrict__ smod, const float* __restrict__ wsq,
    float* __restrict__ demod,
    const float* __restrict__ xin, ushort* __restrict__ xt) {
  int bb = blockIdx.x;
  if (bb < 1024) {
    int wid  = (bb << 2) + (threadIdx.x >> 6);
    int lane = threadIdx.x & 63;
    int b  = wid >> 9;
    int oc = wid & 511;
    const float* s = smod + b * CIN;
    const float* w = wsq + (size_t)oc * CIN;
    float sum = 0.f;
#pragma unroll
    for (int k = 0; k < CIN / 64; ++k) {
      float sv = s[lane + 64 * k];
      sum += sv * sv * w[lane + 64 * k];
    }
#pragma unroll
    for (int off = 32; off; off >>= 1) sum += __shfl_down(sum, off, 64);
    if (lane == 0) demod[wid] = rsqrtf(sum * CONV_SCALE2 + 1e-8f) * CONV_SCALE;
  } else {
    int n = (bb - 1024) * 256 + threadIdx.x;   // < 2,097,152
    int kg = n & 3;
    int x  = (n >> 2) & 63;
    int y  = (n >> 8) & 63;
    int g  = (n >> 14) & 15;
    int b  = n >> 18;
    int ic0 = g * 32 + kg * 8;
    const float* sp = smod + b * CIN + ic0;
    const float* xp = xin + (((size_t)b * CIN + ic0) * HH + y) * WW + x;
    s16x8 o;
#pragma unroll
    for (int j = 0; j < 8; ++j) {
      float v = xp[(size_t)j * HH * WW] * sp[j];
      o[j] = (short)f2bf(v);
    }
    *(s16x8*)(xt + (size_t)n * 8) = o;
  }
}

// ---------------------------------------------------------------------------
// conv_mfma (R15): R14 with the LAST-GBODY vmcnt race fixed.
// R14's bug: in the final GBODY (no stage6), only 4 VM ops are outstanding
// at E(p7)/E(p8), so vmcnt(8) was a NO-OP -> AREAD(7)/AREAD(8) could read a
// ws buffer whose DMA hadn't landed (intermittent: passed call 1, failed a
// timed replay). Fix: peel the last GBODY; all loop bodies now run stage6
// unconditionally (vmcnt ledger exact: p0..p6 = 2, p7/p8 = 8), and the
// peeled GBODY_LAST uses full vmcnt(0) drains at p7/p8 (one-time ~500 cyc)
// and skips WSISSUE(7)/(8) (also removes past-end wfrag reads).
// stage6 always issues exactly 6 DMAs (edge rows -> LDS trash row, R14 fix).
// ---------------------------------------------------------------------------
#define XS_ROW 4224                 // 66 cols * 4 kg * 16 B
#define XS_BUF (6 * XS_ROW)         // 25344 B per buffer
#define WS_BUFSZ 8192               // one kstep of block weights (128oc x 32ic)

#define MFMA1(A_, B_, C_) __builtin_amdgcn_mfma_f32_32x32x16_bf16(A_, B_, C_, 0, 0, 0)

// one k-half (8 MFMAs)
#define MHK(KF, SX, SY) \
  __builtin_amdgcn_s_setprio(1); \
  acc[0][0] = MFMA1(wA[KF],     SX[0 + (KF)], acc[0][0]); \
  acc[1][0] = MFMA1(wA[2 + KF], SX[0 + (KF)], acc[1][0]); \
  acc[0][1] = MFMA1(wA[KF],     SX[2 + (KF)], acc[0][1]); \
  acc[1][1] = MFMA1(wA[2 + KF], SX[2 + (KF)], acc[1][1]); \
  acc[0][2] = MFMA1(wA[KF],     SY[0 + (KF)], acc[0][2]); \
  acc[1][2] = MFMA1(wA[2 + KF], SY[0 + (KF)], acc[1][2]); \
  acc[0][3] = MFMA1(wA[KF],     SY[2 + (KF)], acc[0][3]); \
  acc[1][3] = MFMA1(wA[2 + KF], SY[2 + (KF)], acc[1][3]); \
  __builtin_amdgcn_s_setprio(0);

// B-slot load: xs row (wr2 + RR) at x-shift DXI; frags [ph*2+ks]
#define LOADSLOT(S, RR, DXI) \
  S[0] = *(const s16x8*)(xs_r + (wr2 + (RR)) * XS_ROW + addrV[0][DXI][0]); \
  S[1] = *(const s16x8*)(xs_r + (wr2 + (RR)) * XS_ROW + addrV[0][DXI][1]); \
  S[2] = *(const s16x8*)(xs_r + (wr2 + (RR)) * XS_ROW + addrV[1][DXI][0]); \
  S[3] = *(const s16x8*)(xs_r + (wr2 + (RR)) * XS_ROW + addrV[1][DXI][1]);

// entry barriers: counted vmcnt
#define ENTRYB2 \
  __builtin_amdgcn_sched_barrier(0); \
  asm volatile("s_waitcnt vmcnt(2) lgkmcnt(0)" ::: "memory"); \
  __builtin_amdgcn_sched_barrier(0); \
  __builtin_amdgcn_s_barrier(); \
  __builtin_amdgcn_sched_barrier(0);

#define ENTRYB8 \
  __builtin_amdgcn_sched_barrier(0); \
  asm volatile("s_waitcnt vmcnt(8) lgkmcnt(0)" ::: "memory"); \
  __builtin_amdgcn_sched_barrier(0); \
  __builtin_amdgcn_s_barrier(); \
  __builtin_amdgcn_sched_barrier(0);

#define ENTRYB0 \
  __builtin_amdgcn_sched_barrier(0); \
  asm volatile("s_waitcnt vmcnt(0) lgkmcnt(0)" ::: "memory"); \
  __builtin_amdgcn_sched_barrier(0); \
  __builtin_amdgcn_s_barrier(); \
  __builtin_amdgcn_sched_barrier(0);

// A-fragment reads for this kstep from ws buffer (P % 3)
#define AREAD(P) { \
  const char* wsp_ = wsL + ((P) % 3) * WS_BUFSZ + aoff; \
  wA[0] = *(const s16x8*)(wsp_); \
  wA[1] = *(const s16x8*)(wsp_ + 1024); \
  wA[2] = *(const s16x8*)(wsp_ + 2048); \
  wA[3] = *(const s16x8*)(wsp_ + 3072); }

// issue ws DMA for kstep (g*9 + P + 2) into buffer (P+2)%3
#define WSISSUE(P) { \
  const char* ws_s = wsg + (size_t)((P) + 2) * 32768; \
  char* ws_d = wsdst + (((P) + 2) % 3) * WS_BUFSZ; \
  gload_lds16(ws_s, ws_d); \
  gload_lds16(ws_s + 4096, ws_d + 4096); }

// normal body: stage6 ALWAYS runs at p6 -> vmcnt ledger exact everywhere
#define GBODY(GG) \
{ \
  const char* xs_r = (const char*)lds + (GG) * XS_BUF; \
  char* xs_w = lds + ((GG) ^ 1) * XS_BUF; \
  const char* wsg = wssrcb + (size_t)(g2 * 18 + (GG) * 9) * 32768; \
  /*p0*/ ENTRYB2 AREAD(0) \
         LOADSLOT(bA, 0, 0) LOADSLOT(bB, 1, 0) \
         WSISSUE(0) \
         MHK(0, bA, bB) LOADSLOT(bC, 2, 0) MHK(1, bA, bB) \
  /*p1*/ ENTRYB2 AREAD(1) WSISSUE(1) \
         MHK(0, bB, bC) LOADSLOT(bA, 3, 0) MHK(1, bB, bC) \
  /*p2*/ ENTRYB2 AREAD(2) WSISSUE(2) \
         MHK(0, bC, bA) LOADSLOT(bB, 0, 1) MHK(1, bC, bA) LOADSLOT(bC, 1, 1) \
  /*p3*/ ENTRYB2 AREAD(3) WSISSUE(3) \
         MHK(0, bB, bC) LOADSLOT(bA, 2, 1) MHK(1, bB, bC) \
  /*p4*/ ENTRYB2 AREAD(4) WSISSUE(4) \
         MHK(0, bC, bA) LOADSLOT(bB, 3, 1) MHK(1, bC, bA) \
  /*p5*/ ENTRYB2 AREAD(5) WSISSUE(5) \
         MHK(0, bA, bB) LOADSLOT(bC, 0, 2) MHK(1, bA, bB) LOADSLOT(bA, 1, 2) \
  /*p6*/ ENTRYB2 AREAD(6) WSISSUE(6) \
         stage6(xtb, (size_t)(b * 16 + g2 * 2 + (GG) + 1) * 262144, srcoff, xs_w, trash, lds_woff, y0); \
         MHK(0, bC, bA) LOADSLOT(bB, 2, 2) MHK(1, bC, bA) \
  /*p7*/ ENTRYB8 AREAD(7) WSISSUE(7) \
         MHK(0, bA, bB) LOADSLOT(bC, 3, 2) MHK(1, bA, bB) \
  /*p8*/ ENTRYB8 AREAD(8) WSISSUE(8) \
         MHK(0, bB, bC) MHK(1, bB, bC) \
}

// peeled final body (g2=7, GG=1): no stage6, no WSISSUE(7)/(8); p7/p8 use
// full vmcnt(0) drains (one-time cost) so AREAD(7)/(8) are always safe.
#define GBODY_LAST \
{ \
  const char* xs_r = (const char*)lds + XS_BUF; \
  const char* wsg = wssrcb + (size_t)(7 * 18 + 9) * 32768; \
  /*p0*/ ENTRYB2 AREAD(0) \
         LOADSLOT(bA, 0, 0) LOADSLOT(bB, 1, 0) \
         WSISSUE(0) \
         MHK(0, bA, bB) LOADSLOT(bC, 2, 0) MHK(1, bA, bB) \
  /*p1*/ ENTRYB2 AREAD(1) WSISSUE(1) \
         MHK(0, bB, bC) LOADSLOT(bA, 3, 0) MHK(1, bB, bC) \
  /*p2*/ ENTRYB2 AREAD(2) WSISSUE(2) \
         MHK(0, bC, bA) LOADSLOT(bB, 0, 1) MHK(1, bC, bA) LOADSLOT(bC, 1, 1) \
  /*p3*/ ENTRYB2 AREAD(3) WSISSUE(3) \
         MHK(0, bB, bC) LOADSLOT(bA, 2, 1) MHK(1, bB, bC) \
  /*p4*/ ENTRYB2 AREAD(4) WSISSUE(4) \
         MHK(0, bC, bA) LOADSLOT(bB, 3, 1) MHK(1, bC, bA) \
  /*p5*/ ENTRYB2 AREAD(5) WSISSUE(5) \
         MHK(0, bA, bB) LOADSLOT(bC, 0, 2) MHK(1, bA, bB) LOADSLOT(bA, 1, 2) \
  /*p6*/ ENTRYB2 AREAD(6) WSISSUE(6) \
         MHK(0, bC, bA) LOADSLOT(bB, 2, 2) MHK(1, bC, bA) \
  /*p7*/ ENTRYB0 AREAD(7) \
         MHK(0, bA, bB) LOADSLOT(bC, 3, 2) MHK(1, bA, bB) \
  /*p8*/ ENTRYB0 AREAD(8) \
         MHK(0, bB, bC) MHK(1, bB, bC) \
}

// ALWAYS issues exactly 6 DMAs: out-of-range rows go to the LDS trash row
// (source clamped to a valid row) so vmcnt counts are uniform across blocks
// and the pre-zeroed halo rows are never overwritten.
__device__ __forceinline__ void stage6(const char* xtb, size_t gbase, int srcoff,
                                       char* xs_w, char* trash, int lds_woff, int y0) {
  __builtin_amdgcn_sched_barrier(0);
#pragma unroll
  for (int r = 0; r < 6; ++r) {
    int gy = y0 - 1 + r;
    bool ok = (gy >= 0) && (gy < HH);
    int gyc = ok ? gy : (gy < 0 ? 0 : HH - 1);
    char* dst = ok ? (xs_w + r * XS_ROW + lds_woff) : (trash + lds_woff);
    gload_lds16(xtb + gbase + (size_t)gyc * 4096 + srcoff, dst);
  }
  __builtin_amdgcn_sched_barrier(0);
}

__global__ __launch_bounds__(256, 2) void conv_mfma(
    const ushort* __restrict__ xt,     // [8][16][64][64][32] bf16
    const ushort* __restrict__ wfrag,  // [144][16][2][64][8] bf16
    const float* __restrict__ demod,
    float* __restrict__ out) {
  // 2 xs buffers + 3 ws buffers + 1 trash row = 79488 B -> 2 blocks/CU
  __shared__ char lds[2 * XS_BUF + 3 * WS_BUFSZ + XS_ROW];

  int tid = threadIdx.x;
  int l = tid & 63, w = tid >> 6;
  int wm = w >> 1, wr = w & 1;        // oc-half, row-pair
  int wr2 = wr * 2;
  int bid = blockIdx.x;
  int ocb = bid & 3;
  int b   = (bid >> 2) & 7;
  int yt  = bid >> 5;                 // 0..15
  int y0  = yt * 4;

  const char* wsL = (const char*)lds + 2 * XS_BUF;
  char* wsdst = lds + 2 * XS_BUF + tid * 16;
  char* trash = lds + 2 * XS_BUF + 3 * WS_BUFSZ;

  f32x16 acc[2][4];
#pragma unroll
  for (int i = 0; i < 2; ++i)
#pragma unroll
    for (int j = 0; j < 4; ++j)
#pragma unroll
      for (int e = 0; e < 16; ++e) acc[i][j][e] = 0.f;

  // zero always-zero halo COLUMNS (col 0 -> chunks 0..3, col 65 -> 260..263)
  if (tid < 96) {
    int buf = tid & 1, side = (tid >> 1) & 1, kgz = (tid >> 2) & 3, r = tid >> 4;
    int chunk = side ? (260 + kgz) : kgz;
    *(int4*)(lds + buf * XS_BUF + r * XS_ROW + chunk * 16) = int4{0, 0, 0, 0};
  }
  // zero y-halo ROWS for edge blocks (never re-staged -> stay zero)
  if (y0 == 0) {
    for (int i = tid; i < 512; i += 256) {
      int buf = i & 1, chunk = 4 + (i >> 1);
      *(int4*)(lds + buf * XS_BUF + chunk * 16) = int4{0, 0, 0, 0};
    }
  }
  if (y0 == 60) {
    for (int i = tid; i < 512; i += 256) {
      int buf = i & 1, chunk = 4 + (i >> 1);
      *(int4*)(lds + buf * XS_BUF + 5 * XS_ROW + chunk * 16) = int4{0, 0, 0, 0};
    }
  }

  // B-fragment read offsets (swizzled): col = ph*32 + (l&31) + dxi,
  // kg = (l>>5) + 2*ks;  addr = (col*4 + (kg ^ ((col>>1)&3))) * 16
  int addrV[2][3][2];
  {
    int lm = l & 31, kh2 = l >> 5;
#pragma unroll
    for (int ph = 0; ph < 2; ++ph)
#pragma unroll
      for (int dxi = 0; dxi < 3; ++dxi)
#pragma unroll
        for (int ks = 0; ks < 2; ++ks) {
          int col = ph * 32 + lm + dxi;                    // 0..65
          int kg  = kh2 + 2 * ks;
          addrV[ph][dxi][ks] = (col * 4 + (kg ^ ((col >> 1) & 3))) * 16;
        }
  }

  // xs staging: wave w covers quarter w of each row; per-lane PRE-SWIZZLED
  // global source offset within a 4KB xt row (verified R5-R12)
  int col_s = 1 + w * 16 + (l >> 2);
  int srcoff = (col_s - 1) * 64 + ((l & 3) ^ ((col_s >> 1) & 3)) * 16;
  int lds_woff = 64 + w * 1024;   // + r*XS_ROW (+buf*XS_BUF)

  const char* xtb = (const char*)xt;
  // ws DMA source base: per-thread 16B chunk of the block's 8KB kstep slice
  const char* wssrcb = (const char*)wfrag + (size_t)ocb * 8192 + (size_t)tid * 16;
  // A ds_read base offset: (mf_local = wm*2+q)*2048 + ks*1024 + l*16
  int aoff = wm * 4096 + l * 16;

  // prologue: stage xs(g0), ws(k0), ws(k1); drained by __syncthreads
  {
    size_t gbase = (size_t)(b * 16) * 262144;
#pragma unroll
    for (int r = 0; r < 6; ++r) {
      int gy = y0 - 1 + r;
      if (gy >= 0 && gy < HH)
        gload_lds16(xtb + gbase + (size_t)gy * 4096 + srcoff,
                    lds + r * XS_ROW + lds_woff);
    }
    gload_lds16(wssrcb,          wsdst);
    gload_lds16(wssrcb + 4096,   wsdst + 4096);
    gload_lds16(wssrcb + 32768,        wsdst + WS_BUFSZ);
    gload_lds16(wssrcb + 32768 + 4096, wsdst + WS_BUFSZ + 4096);
  }
  __syncthreads();

  s16x8 wA[4];
  s16x8 bA[4], bB[4], bC[4];

  for (int g2 = 0; g2 < 7; ++g2) {
    GBODY(0)
    GBODY(1)
  }
  {
    const int g2 = 7;
    GBODY(0)
    GBODY_LAST
  }

  // ---- epilogue: demod scale + store ----
  // C/D 32x32: col = l&31, row = (reg&3) + 8*(reg>>2) + 4*(l>>5)
  int gy_base = y0 + wr2;
  int colbase = l & 31;
  int rowadd = 4 * (l >> 5);
#pragma unroll
  for (int q = 0; q < 2; ++q) {
#pragma unroll
    for (int reg = 0; reg < 16; ++reg) {
      int row = (reg & 3) + 8 * (reg >> 2) + rowadd;
      int oc = ocb * 128 + (wm * 2 + q) * 32 + row;
      float dm = demod[b * COUT + oc];
#pragma unroll
      for (int n = 0; n < 4; ++n) {
        int gy = gy_base + (n >> 1);
        int px = (n & 1) * 32 + colbase;
        out[((size_t)(b * COUT + oc)) * 4096 + gy * 64 + px] = acc[q][n][reg] * dm;
      }
    }
  }
}

// ---------------------------------------------------------------------------
extern "C" void kernel_launch(void* const* d_in, const int* in_sizes, int n_in,
                              void* d_out, int out_size, void* d_ws, size_t ws_size,
                              hipStream_t stream) {
  const float* input = (const float*)d_in[0];  // [8,512,64,64]
  const float* style = (const float*)d_in[1];  // [8,512]
  const float* wa    = (const float*)d_in[2];  // [512,512]
  const float* ba    = (const float*)d_in[3];  // [1,512]
  const float* wconv = (const float*)d_in[4];  // [512,512,3,3]
  float* out = (float*)d_out;

  float* smod  = (float*)d_ws;                    // 4096 f
  float* demod = smod + BB * CIN;                 // 4096 f
  float* wsq   = demod + BB * COUT;               // 262144 f
  ushort* wfrag = (ushort*)(wsq + (size_t)COUT * CIN);   // 2,359,296 us (4.5 MB)
  ushort* xt    = wfrag + (size_t)16 * 9 * 32 * 64 * 8;  // 16,777,216 us (32 MB)

  prep1_kernel<<<3200, 256, 0, stream>>>(style, wa, ba, smod, wconv, wsq, wfrag);
  prep2_kernel<<<9216, 256, 0, stream>>>(smod, wsq, demod, input, xt);
  conv_mfma<<<BB * 4 * 16, 256, 0, stream>>>(xt, wfrag, demod, out);
}